// Round 1
// baseline (4027.582 us; speedup 1.0000x reference)
//
#include <hip/hip_runtime.h>
#include <math.h>

// ---- NSA hyperparameters (compile-time, matches reference config) ----
constexpr int kT    = 2048;
constexpr int kHQ   = 16;
constexpr int kD    = 128;
constexpr int kKS   = 32;
constexpr int kST   = 16;
constexpr int kBS   = 64;
constexpr int kM    = (kT - kKS) / kST + 1;   // 127 compressed tokens
constexpr int kNB   = (kT + kBS - 1) / kBS;   // 32 selection blocks
constexpr int kTopN = 16;
constexpr int kNInit = 2;
constexpr int kWIN  = 512;
constexpr float kNEG = -1e30f;
constexpr float kBIG = 1e30f;
constexpr float kScale = 0.08838834764831845f; // 128^-0.5

// K2 LDS strides (padded to dodge bank conflicts)
constexpr int kQStride = kD + 4;   // 132 floats
constexpr int kPStride = kM + 2;   // 129 floats

// ---------------------------------------------------------------------
// K1: mean-pool compressed K/V.  grid=(M), block=(D)
// ---------------------------------------------------------------------
__global__ void k_compress(const float* __restrict__ k, const float* __restrict__ v,
                           float* __restrict__ cmp_k, float* __restrict__ cmp_v) {
    const int m = blockIdx.x;
    const int d = threadIdx.x;
    float sk = 0.f, sv = 0.f;
    const int base = m * kST;
    #pragma unroll
    for (int i = 0; i < kKS; ++i) {
        sk += k[(size_t)(base + i) * kD + d];
        sv += v[(size_t)(base + i) * kD + d];
    }
    cmp_k[m * kD + d] = sk * (1.0f / kKS);
    cmp_v[m * kD + d] = sv * (1.0f / kKS);
}

// ---------------------------------------------------------------------
// K2: compressed attention for all 16 heads of one query t.
// Writes w0*cmp_o into out, and slc_p[t][NB] block scores.
// grid=(T), block=(256)
// ---------------------------------------------------------------------
__global__ __launch_bounds__(256) void k_cmp_attn(
        const float* __restrict__ q, const float* __restrict__ cw,
        const float* __restrict__ cmp_k, const float* __restrict__ cmp_v,
        float* __restrict__ slc_p, float* __restrict__ out) {
    const int t = blockIdx.x;
    const int tid = threadIdx.x;

    __shared__ float q_s[kHQ * kQStride];   // 16 x 132
    __shared__ float p_s[kHQ * kPStride];   // 16 x 129 (scores -> probs)

    // load q[t, :, :]
    for (int i = tid; i < kHQ * kD; i += 256) {
        int h = i >> 7, d = i & 127;
        q_s[h * kQStride + d] = q[(size_t)t * kHQ * kD + i];
    }
    __syncthreads();

    const int nvalid = (t >= kKS - 1) ? min(kM, (t - (kKS - 1)) / kST + 1) : 0;

    // scores: idx = m*HQ + h so 16 consecutive threads share one cmp_k row
    for (int idx = tid; idx < kHQ * kM; idx += 256) {
        const int m = idx / kHQ;
        const int h = idx % kHQ;
        float s = kNEG;
        if (m < nvalid) {
            const float4* k4 = (const float4*)(cmp_k + (size_t)m * kD);
            const float4* q4 = (const float4*)(q_s + h * kQStride);
            float acc = 0.f;
            #pragma unroll
            for (int i = 0; i < kD / 4; ++i) {
                float4 a = q4[i]; float4 b = k4[i];
                acc = fmaf(a.x, b.x, fmaf(a.y, b.y, fmaf(a.z, b.z, fmaf(a.w, b.w, acc))));
            }
            s = acc * kScale;
        }
        p_s[h * kPStride + m] = s;
    }
    __syncthreads();

    // softmax per head (one thread per head, serial over 127)
    if (tid < kHQ) {
        float* p = p_s + tid * kPStride;
        if (nvalid == 0) {
            for (int m = 0; m < kM; ++m) p[m] = 0.f;
        } else {
            float mx = kNEG;
            for (int m = 0; m < nvalid; ++m) mx = fmaxf(mx, p[m]);
            float l = 0.f;
            for (int m = 0; m < nvalid; ++m) { float e = __expf(p[m] - mx); p[m] = e; l += e; }
            float inv = 1.f / l;
            for (int m = 0; m < nvalid; ++m) p[m] *= inv;
            for (int m = nvalid; m < kM; ++m) p[m] = 0.f;
        }
    }
    __syncthreads();

    // cmp_o scaled by sigmoid(cw0) -> out
    for (int idx = tid; idx < kHQ * kD; idx += 256) {
        const int h = idx >> 7;
        const int d = idx & 127;
        const float* p = p_s + h * kPStride;
        float acc = 0.f;
        for (int m = 0; m < nvalid; ++m)
            acc = fmaf(p[m], cmp_v[(size_t)m * kD + d], acc);
        const float c0 = cw[((size_t)t * kHQ + h) * 3 + 0];
        const float w0 = 1.f / (1.f + __expf(-c0));
        out[((size_t)t * kHQ + h) * kD + d] = w0 * acc;
    }

    // slc_p[t][b] = sum_h sum_m p[h][m] * Wmap[m][b]
    // Wmap: w=1 for m=4b,4b+1,4b+2 ; w=0.5 for m=4b+3 and m=4b-1
    if (tid < kNB) {
        const int b = tid;
        const int m0 = 4 * b;
        float acc = 0.f;
        for (int h = 0; h < kHQ; ++h) {
            const float* p = p_s + h * kPStride;
            float a = 0.f;
            if (m0     < kM) a += p[m0];
            if (m0 + 1 < kM) a += p[m0 + 1];
            if (m0 + 2 < kM) a += p[m0 + 2];
            if (m0 + 3 < kM) a += 0.5f * p[m0 + 3];
            if (m0 - 1 >= 0) a += 0.5f * p[m0 - 1];
            acc += a;
        }
        slc_p[t * kNB + b] = acc;
    }
}

// ---------------------------------------------------------------------
// K3: top-k block selection -> 32-bit mask per t.  1 thread per t.
// Matches jax.lax.top_k semantics (desc value, stable lowest-index ties).
// ---------------------------------------------------------------------
__global__ void k_topk(const float* __restrict__ slc_p, unsigned* __restrict__ sel_mask) {
    const int t = blockIdx.x * blockDim.x + threadIdx.x;
    if (t >= kT) return;
    const int cur = t / kBS;
    float vals[kNB];
    #pragma unroll
    for (int b = 0; b < kNB; ++b) {
        float x = slc_p[t * kNB + b];
        if (b > cur) x = kNEG;                        // future
        if (b < kNInit || b == cur) x = kBIG;         // forced (NLOCAL=1)
        vals[b] = x;
    }
    unsigned mask = 0;
    for (int n = 0; n < kTopN; ++n) {
        float best = -3.0e38f; int bi = 0;
        #pragma unroll
        for (int b = 0; b < kNB; ++b) {
            bool taken = (mask >> b) & 1u;
            if (!taken && vals[b] > best) { best = vals[b]; bi = b; }
        }
        mask |= (1u << bi);
    }
    sel_mask[t] = mask;
}

// ---------------------------------------------------------------------
// K4: select attention + sliding-window attention + combine.
// grid=(T, HQ), block=(128).  out += w1*sel_o + w2*swa_o
// ---------------------------------------------------------------------
__global__ __launch_bounds__(128) void k_sel_swa(
        const float* __restrict__ q, const float* __restrict__ kk,
        const float* __restrict__ vv, const float* __restrict__ cw,
        const unsigned* __restrict__ sel_mask, float* __restrict__ out) {
    const int t = blockIdx.x;
    const int h = blockIdx.y;
    const int tid = threadIdx.x;

    __shared__ float q_s[kD];
    __shared__ float sc[kTopN * kBS];   // 1024 score slots (reused by swa)
    __shared__ float red[4];
    __shared__ int   blist[kTopN];
    __shared__ int   nb_s;

    q_s[tid] = q[((size_t)t * kHQ + h) * kD + tid];
    if (tid == 0) {
        unsigned mask = sel_mask[t];
        int nb = 0;
        for (int b = 0; b < kNB; ++b)
            if ((mask >> b) & 1u) { if (nb < kTopN) blist[nb] = b; ++nb; }
        nb_s = (nb > kTopN) ? kTopN : nb;
    }
    __syncthreads();
    const int nb = nb_s;
    const int nslots = nb * kBS;

    // ---- select scores ----
    for (int slot = tid; slot < nslots; slot += 128) {
        const int b = blist[slot >> 6];
        const int s = (b << 6) + (slot & 63);
        float val = kNEG;
        if (s <= t) {
            const float4* k4 = (const float4*)(kk + (size_t)s * kD);
            const float4* q4 = (const float4*)q_s;
            float acc = 0.f;
            #pragma unroll
            for (int i = 0; i < kD / 4; ++i) {
                float4 a = q4[i]; float4 b4 = k4[i];
                acc = fmaf(a.x, b4.x, fmaf(a.y, b4.y, fmaf(a.z, b4.z, fmaf(a.w, b4.w, acc))));
            }
            val = acc * kScale;
        }
        sc[slot] = val;
    }
    __syncthreads();

    float mx = kNEG;
    for (int slot = tid; slot < nslots; slot += 128) mx = fmaxf(mx, sc[slot]);
    #pragma unroll
    for (int off = 32; off; off >>= 1) mx = fmaxf(mx, __shfl_xor(mx, off));
    if ((tid & 63) == 0) red[tid >> 6] = mx;
    __syncthreads();
    mx = fmaxf(red[0], red[1]);

    float l = 0.f;
    for (int slot = tid; slot < nslots; slot += 128) {
        float e = __expf(sc[slot] - mx); sc[slot] = e; l += e;
    }
    #pragma unroll
    for (int off = 32; off; off >>= 1) l += __shfl_xor(l, off);
    if ((tid & 63) == 0) red[2 + (tid >> 6)] = l;
    __syncthreads();
    l = red[2] + red[3];
    const float inv_sel = 1.f / l;

    float acc_sel = 0.f;
    for (int i = 0; i < nb; ++i) {
        const int s0b = blist[i] << 6;
        if (s0b > t) continue;
        const int cnt = min(kBS, t - s0b + 1);
        const float* vp = vv + (size_t)s0b * kD + tid;
        const float* pp = sc + i * kBS;
        for (int j = 0; j < cnt; ++j)
            acc_sel = fmaf(pp[j], vp[(size_t)j * kD], acc_sel);
    }
    acc_sel *= inv_sel;
    __syncthreads();   // everyone done reading sc

    // ---- sliding window ----
    const int s0 = max(0, t - kWIN + 1);
    const int n = t - s0 + 1;
    for (int slot = tid; slot < n; slot += 128) {
        const int s = s0 + slot;
        const float4* k4 = (const float4*)(kk + (size_t)s * kD);
        const float4* q4 = (const float4*)q_s;
        float acc = 0.f;
        #pragma unroll
        for (int i = 0; i < kD / 4; ++i) {
            float4 a = q4[i]; float4 b4 = k4[i];
            acc = fmaf(a.x, b4.x, fmaf(a.y, b4.y, fmaf(a.z, b4.z, fmaf(a.w, b4.w, acc))));
        }
        sc[slot] = acc * kScale;
    }
    __syncthreads();

    mx = kNEG;
    for (int slot = tid; slot < n; slot += 128) mx = fmaxf(mx, sc[slot]);
    #pragma unroll
    for (int off = 32; off; off >>= 1) mx = fmaxf(mx, __shfl_xor(mx, off));
    if ((tid & 63) == 0) red[tid >> 6] = mx;
    __syncthreads();
    mx = fmaxf(red[0], red[1]);

    l = 0.f;
    for (int slot = tid; slot < n; slot += 128) {
        float e = __expf(sc[slot] - mx); sc[slot] = e; l += e;
    }
    #pragma unroll
    for (int off = 32; off; off >>= 1) l += __shfl_xor(l, off);
    if ((tid & 63) == 0) red[2 + (tid >> 6)] = l;
    __syncthreads();
    l = red[2] + red[3];
    const float inv_swa = 1.f / l;

    float acc_swa = 0.f;
    {
        const float* vp = vv + (size_t)s0 * kD + tid;
        for (int j = 0; j < n; ++j)
            acc_swa = fmaf(sc[j], vp[(size_t)j * kD], acc_swa);
    }
    acc_swa *= inv_swa;

    // ---- combine ----
    const float c1 = cw[((size_t)t * kHQ + h) * 3 + 1];
    const float c2 = cw[((size_t)t * kHQ + h) * 3 + 2];
    const float w1 = 1.f / (1.f + __expf(-c1));
    const float w2 = 1.f / (1.f + __expf(-c2));
    out[((size_t)t * kHQ + h) * kD + tid] += w1 * acc_sel + w2 * acc_swa;
}

// ---------------------------------------------------------------------
extern "C" void kernel_launch(void* const* d_in, const int* in_sizes, int n_in,
                              void* d_out, int out_size, void* d_ws, size_t ws_size,
                              hipStream_t stream) {
    const float* q  = (const float*)d_in[0];
    const float* k  = (const float*)d_in[1];
    const float* v  = (const float*)d_in[2];
    const float* cw = (const float*)d_in[3];
    // d_in[4] = cu_seqlens [0, T] : single sequence, unused.
    float* out = (float*)d_out;

    float* ws = (float*)d_ws;
    float* cmp_k = ws;                         // M*D
    float* cmp_v = ws + kM * kD;               // M*D
    float* slc_p = ws + 2 * kM * kD;           // T*NB
    unsigned* sel_mask = (unsigned*)(ws + 2 * kM * kD + kT * kNB);  // T

    k_compress<<<dim3(kM), dim3(kD), 0, stream>>>(k, v, cmp_k, cmp_v);
    k_cmp_attn<<<dim3(kT), dim3(256), 0, stream>>>(q, cw, cmp_k, cmp_v, slc_p, out);
    k_topk<<<dim3(kT / 256), dim3(256), 0, stream>>>(slc_p, sel_mask);
    k_sel_swa<<<dim3(kT, kHQ), dim3(128), 0, stream>>>(q, k, v, cw, sel_mask, out);
}

// Round 2
// 394.061 us; speedup vs baseline: 10.2207x; 10.2207x over previous
//
#include <hip/hip_runtime.h>
#include <math.h>

// ---- NSA hyperparameters (compile-time, matches reference config) ----
constexpr int kT    = 2048;
constexpr int kHQ   = 16;
constexpr int kD    = 128;
constexpr int kKS   = 32;
constexpr int kST   = 16;
constexpr int kBS   = 64;
constexpr int kM    = (kT - kKS) / kST + 1;   // 127 compressed tokens
constexpr int kNB   = (kT + kBS - 1) / kBS;   // 32 selection blocks
constexpr int kTopN = 16;
constexpr int kNInit = 2;
constexpr int kWIN  = 512;
constexpr float kNEG = -1e30f;
constexpr float kBIG = 1e30f;
constexpr float kScale = 0.08838834764831845f; // 128^-0.5

constexpr int kQStride = kD + 4;   // K2 LDS pad
constexpr int kPStride = kM + 2;

constexpr int kPad    = 32;        // tile-tail padding rows/cols
constexpr int kKBRows = kT + kPad; // 2080
constexpr int kVTCols = kT + kPad; // 2080
constexpr int kSStride = 17;       // S[slot][head] stride (odd -> conflict-free)
constexpr int kSlotMax = 1024;     // 16 blocks * 64

typedef __attribute__((ext_vector_type(8))) short short8;
typedef __attribute__((ext_vector_type(4))) float floatx4;

// RNE float -> bf16 bits (inputs are normal floats)
__device__ inline short f2bf(float x) {
    unsigned u = __float_as_uint(x);
    unsigned r = (u + 0x7fffu + ((u >> 16) & 1u)) >> 16;
    return (short)r;
}

// ---------------------------------------------------------------------
// K1: mean-pool compressed K/V.  grid=(M), block=(D)
// ---------------------------------------------------------------------
__global__ void k_compress(const float* __restrict__ k, const float* __restrict__ v,
                           float* __restrict__ cmp_k, float* __restrict__ cmp_v) {
    const int m = blockIdx.x;
    const int d = threadIdx.x;
    float sk = 0.f, sv = 0.f;
    const int base = m * kST;
    #pragma unroll
    for (int i = 0; i < kKS; ++i) {
        sk += k[(size_t)(base + i) * kD + d];
        sv += v[(size_t)(base + i) * kD + d];
    }
    cmp_k[m * kD + d] = sk * (1.0f / kKS);
    cmp_v[m * kD + d] = sv * (1.0f / kKS);
}

// ---------------------------------------------------------------------
// K1b: fp32 -> bf16 staging.  kb[row][d] row-major (rows 2048.. zero),
// vt[d][row] dim-major transposed (cols 2048.. zero).  grid=(2080), block=(128)
// ---------------------------------------------------------------------
__global__ void k_convert(const float* __restrict__ k, const float* __restrict__ v,
                          short* __restrict__ kb, short* __restrict__ vt) {
    const int row = blockIdx.x;
    const int d = threadIdx.x;
    if (row < kT) {
        kb[row * kD + d] = f2bf(k[(size_t)row * kD + d]);
        vt[(size_t)d * kVTCols + row] = f2bf(v[(size_t)row * kD + d]);
    } else {
        kb[row * kD + d] = 0;
        vt[(size_t)d * kVTCols + row] = 0;
    }
}

// ---------------------------------------------------------------------
// K2: compressed attention, all 16 heads of one t.  (unchanged from R1)
// ---------------------------------------------------------------------
__global__ __launch_bounds__(256) void k_cmp_attn(
        const float* __restrict__ q, const float* __restrict__ cw,
        const float* __restrict__ cmp_k, const float* __restrict__ cmp_v,
        float* __restrict__ slc_p, float* __restrict__ out) {
    const int t = blockIdx.x;
    const int tid = threadIdx.x;

    __shared__ float q_s[kHQ * kQStride];
    __shared__ float p_s[kHQ * kPStride];

    for (int i = tid; i < kHQ * kD; i += 256) {
        int h = i >> 7, d = i & 127;
        q_s[h * kQStride + d] = q[(size_t)t * kHQ * kD + i];
    }
    __syncthreads();

    const int nvalid = (t >= kKS - 1) ? min(kM, (t - (kKS - 1)) / kST + 1) : 0;

    for (int idx = tid; idx < kHQ * kM; idx += 256) {
        const int m = idx / kHQ;
        const int h = idx % kHQ;
        float s = kNEG;
        if (m < nvalid) {
            const float4* k4 = (const float4*)(cmp_k + (size_t)m * kD);
            const float4* q4 = (const float4*)(q_s + h * kQStride);
            float acc = 0.f;
            #pragma unroll
            for (int i = 0; i < kD / 4; ++i) {
                float4 a = q4[i]; float4 b = k4[i];
                acc = fmaf(a.x, b.x, fmaf(a.y, b.y, fmaf(a.z, b.z, fmaf(a.w, b.w, acc))));
            }
            s = acc * kScale;
        }
        p_s[h * kPStride + m] = s;
    }
    __syncthreads();

    if (tid < kHQ) {
        float* p = p_s + tid * kPStride;
        if (nvalid == 0) {
            for (int m = 0; m < kM; ++m) p[m] = 0.f;
        } else {
            float mx = kNEG;
            for (int m = 0; m < nvalid; ++m) mx = fmaxf(mx, p[m]);
            float l = 0.f;
            for (int m = 0; m < nvalid; ++m) { float e = __expf(p[m] - mx); p[m] = e; l += e; }
            float inv = 1.f / l;
            for (int m = 0; m < nvalid; ++m) p[m] *= inv;
            for (int m = nvalid; m < kM; ++m) p[m] = 0.f;
        }
    }
    __syncthreads();

    for (int idx = tid; idx < kHQ * kD; idx += 256) {
        const int h = idx >> 7;
        const int d = idx & 127;
        const float* p = p_s + h * kPStride;
        float acc = 0.f;
        for (int m = 0; m < nvalid; ++m)
            acc = fmaf(p[m], cmp_v[(size_t)m * kD + d], acc);
        const float c0 = cw[((size_t)t * kHQ + h) * 3 + 0];
        const float w0 = 1.f / (1.f + __expf(-c0));
        out[((size_t)t * kHQ + h) * kD + d] = w0 * acc;
    }

    if (tid < kNB) {
        const int b = tid;
        const int m0 = 4 * b;
        float acc = 0.f;
        for (int h = 0; h < kHQ; ++h) {
            const float* p = p_s + h * kPStride;
            float a = 0.f;
            if (m0     < kM) a += p[m0];
            if (m0 + 1 < kM) a += p[m0 + 1];
            if (m0 + 2 < kM) a += p[m0 + 2];
            if (m0 + 3 < kM) a += 0.5f * p[m0 + 3];
            if (m0 - 1 >= 0) a += 0.5f * p[m0 - 1];
            acc += a;
        }
        slc_p[t * kNB + b] = acc;
    }
}

// ---------------------------------------------------------------------
// K3: top-k -> 32-bit block membership mask per t.  (unchanged)
// ---------------------------------------------------------------------
__global__ void k_topk(const float* __restrict__ slc_p, unsigned* __restrict__ sel_mask) {
    const int t = blockIdx.x * blockDim.x + threadIdx.x;
    if (t >= kT) return;
    const int cur = t / kBS;
    float vals[kNB];
    #pragma unroll
    for (int b = 0; b < kNB; ++b) {
        float x = slc_p[t * kNB + b];
        if (b > cur) x = kNEG;
        if (b < kNInit || b == cur) x = kBIG;
        vals[b] = x;
    }
    unsigned mask = 0;
    for (int n = 0; n < kTopN; ++n) {
        float best = -3.0e38f; int bi = 0;
        #pragma unroll
        for (int b = 0; b < kNB; ++b) {
            bool taken = (mask >> b) & 1u;
            if (!taken && vals[b] > best) { best = vals[b]; bi = b; }
        }
        mask |= (1u << bi);
    }
    sel_mask[t] = mask;
}

// ---------------------------------------------------------------------
// K4: MFMA select + SWA attention, all 16 heads of one t.
// grid=(T), block=(256)=4 waves.  out += w1*sel_o + w2*swa_o
// MFMA 16x16x32_bf16: A[m=lane&15][k=quad*8+j], B[n=lane&15][k=quad*8+j],
// D: col=lane&15, row=quad*4+reg  (m89/m120-verified layouts)
// ---------------------------------------------------------------------
__global__ __launch_bounds__(256) void k_attn_mfma(
        const float* __restrict__ q, const short* __restrict__ kb,
        const short* __restrict__ vt, const float* __restrict__ cw,
        const unsigned* __restrict__ sel_mask, float* __restrict__ out) {
    const int t    = blockIdx.x;
    const int tid  = threadIdx.x;
    const int wave = tid >> 6;
    const int lane = tid & 63;
    const int l15  = lane & 15;
    const int quad = lane >> 4;

    __shared__ float S[kSlotMax * kSStride];   // 69632 B score/prob matrix
    __shared__ int   blist[kTopN];
    __shared__ int   nb_s;
    __shared__ float inv_sel[kHQ], inv_swa[kHQ];

    // ---- A-fragments: q[t][head][.] -> bf16, head = l15, k-chunk c ----
    short8 aq[4];
    {
        const float* qp = q + ((size_t)t * kHQ + l15) * kD + quad * 8;
        #pragma unroll
        for (int c = 0; c < 4; ++c) {
            const float4 f0 = *(const float4*)(qp + c * 32);
            const float4 f1 = *(const float4*)(qp + c * 32 + 4);
            short8 a;
            a[0] = f2bf(f0.x); a[1] = f2bf(f0.y); a[2] = f2bf(f0.z); a[3] = f2bf(f0.w);
            a[4] = f2bf(f1.x); a[5] = f2bf(f1.y); a[6] = f2bf(f1.z); a[7] = f2bf(f1.w);
            aq[c] = a;
        }
    }

    if (tid == 0) {
        unsigned mask = sel_mask[t];
        int nb = 0;
        for (int b = 0; b < kNB; ++b)
            if ((mask >> b) & 1u) blist[nb++] = b;
        nb_s = nb;
    }
    __syncthreads();
    const int nb = nb_s;                 // 2..16 blocks, ascending

    // ================= SELECT pass =================
    // QK^T: tiles of 16 keys, tau over nb*4 tiles, wave-strided
    const int ntile_sel = nb * 4;
    for (int tau = wave; tau < ntile_sel; tau += 4) {
        const int key0 = blist[tau >> 2] * kBS + (tau & 3) * 16;
        floatx4 acc = {0.f, 0.f, 0.f, 0.f};
        const short* kp = kb + (size_t)(key0 + l15) * kD + quad * 8;
        #pragma unroll
        for (int c = 0; c < 4; ++c) {
            short8 b = *(const short8*)(kp + c * 32);
            acc = __builtin_amdgcn_mfma_f32_16x16x32_bf16(aq[c], b, acc, 0, 0, 0);
        }
        const int key  = key0 + l15;
        const int slot = tau * 16 + l15;
        const bool ok  = (key <= t);
        #pragma unroll
        for (int r = 0; r < 4; ++r)
            S[slot * kSStride + quad * 4 + r] = ok ? acc[r] * kScale : kNEG;
    }
    __syncthreads();

    // softmax over slots: h = tid>>4, 16 lanes stride the slot dim
    {
        const int h = tid >> 4, j = tid & 15;
        const int ns = nb * kBS;
        float m = kNEG;
        for (int s = j; s < ns; s += 16) m = fmaxf(m, S[s * kSStride + h]);
        #pragma unroll
        for (int off = 8; off; off >>= 1) m = fmaxf(m, __shfl_xor(m, off, 16));
        float l = 0.f;
        for (int s = j; s < ns; s += 16) {
            float e = __expf(S[s * kSStride + h] - m);
            S[s * kSStride + h] = e;
            l += e;
        }
        #pragma unroll
        for (int off = 8; off; off >>= 1) l += __shfl_xor(l, off, 16);
        if (j == 0) inv_sel[h] = 1.f / l;
    }
    __syncthreads();

    // PV: wave owns dims [32w, 32w+32), K-chunks of 32 slots
    const int dimbase = wave * 32;
    floatx4 osel[2] = {{0,0,0,0},{0,0,0,0}};
    const int kc_sel = nb * 2;
    for (int kc = 0; kc < kc_sel; ++kc) {
        short8 ap;
        const int sbase = kc * 32 + quad * 8;
        #pragma unroll
        for (int j = 0; j < 8; ++j)
            ap[j] = f2bf(S[(sbase + j) * kSStride + l15]);
        const int keybase = blist[kc >> 1] * kBS + (kc & 1) * 32;
        #pragma unroll
        for (int nt = 0; nt < 2; ++nt) {
            const short* vp = vt + (size_t)(dimbase + nt * 16 + l15) * kVTCols + keybase + quad * 8;
            short8 b = *(const short8*)vp;
            osel[nt] = __builtin_amdgcn_mfma_f32_16x16x32_bf16(ap, b, osel[nt], 0, 0, 0);
        }
    }
    __syncthreads();   // done reading S

    // ================= SWA pass =================
    const int s0 = max(0, t - kWIN + 1);
    const int n  = t - s0 + 1;
    const int kchunks   = (n + 31) >> 5;
    const int ntile_swa = kchunks * 2;   // cover PV range with NEG-masked tail
    for (int tau = wave; tau < ntile_swa; tau += 4) {
        const int key0 = s0 + tau * 16;
        floatx4 acc = {0.f, 0.f, 0.f, 0.f};
        const short* kp = kb + (size_t)(key0 + l15) * kD + quad * 8;
        #pragma unroll
        for (int c = 0; c < 4; ++c) {
            short8 b = *(const short8*)(kp + c * 32);
            acc = __builtin_amdgcn_mfma_f32_16x16x32_bf16(aq[c], b, acc, 0, 0, 0);
        }
        const int key  = key0 + l15;
        const int slot = tau * 16 + l15;
        const bool ok  = (key <= t);
        #pragma unroll
        for (int r = 0; r < 4; ++r)
            S[slot * kSStride + quad * 4 + r] = ok ? acc[r] * kScale : kNEG;
    }
    __syncthreads();

    {
        const int h = tid >> 4, j = tid & 15;
        const int ns = ntile_swa * 16;
        float m = kNEG;
        for (int s = j; s < ns; s += 16) m = fmaxf(m, S[s * kSStride + h]);
        #pragma unroll
        for (int off = 8; off; off >>= 1) m = fmaxf(m, __shfl_xor(m, off, 16));
        float l = 0.f;
        for (int s = j; s < ns; s += 16) {
            float e = __expf(S[s * kSStride + h] - m);
            S[s * kSStride + h] = e;
            l += e;
        }
        #pragma unroll
        for (int off = 8; off; off >>= 1) l += __shfl_xor(l, off, 16);
        if (j == 0) inv_swa[h] = 1.f / l;
    }
    __syncthreads();

    floatx4 oswa[2] = {{0,0,0,0},{0,0,0,0}};
    for (int kc = 0; kc < kchunks; ++kc) {
        short8 ap;
        const int sbase = kc * 32 + quad * 8;
        #pragma unroll
        for (int j = 0; j < 8; ++j)
            ap[j] = f2bf(S[(sbase + j) * kSStride + l15]);
        const int keybase = s0 + kc * 32;
        #pragma unroll
        for (int nt = 0; nt < 2; ++nt) {
            const short* vp = vt + (size_t)(dimbase + nt * 16 + l15) * kVTCols + keybase + quad * 8;
            short8 b = *(const short8*)vp;
            oswa[nt] = __builtin_amdgcn_mfma_f32_16x16x32_bf16(ap, b, oswa[nt], 0, 0, 0);
        }
    }

    // ================= combine =================
    #pragma unroll
    for (int r = 0; r < 4; ++r) {
        const int head = quad * 4 + r;
        const float c1 = cw[((size_t)t * kHQ + head) * 3 + 1];
        const float c2 = cw[((size_t)t * kHQ + head) * 3 + 2];
        const float w1 = 1.f / (1.f + __expf(-c1));
        const float w2 = 1.f / (1.f + __expf(-c2));
        const float is = inv_sel[head], iw = inv_swa[head];
        #pragma unroll
        for (int nt = 0; nt < 2; ++nt) {
            const int dim = dimbase + nt * 16 + l15;
            float* op = out + ((size_t)t * kHQ + head) * kD + dim;
            *op += w1 * osel[nt][r] * is + w2 * oswa[nt][r] * iw;
        }
    }
}

// ---------------------------------------------------------------------
extern "C" void kernel_launch(void* const* d_in, const int* in_sizes, int n_in,
                              void* d_out, int out_size, void* d_ws, size_t ws_size,
                              hipStream_t stream) {
    const float* q  = (const float*)d_in[0];
    const float* k  = (const float*)d_in[1];
    const float* v  = (const float*)d_in[2];
    const float* cw = (const float*)d_in[3];
    float* out = (float*)d_out;

    float* ws = (float*)d_ws;
    float* cmp_k = ws;                                   // M*D fp32
    float* cmp_v = cmp_k + kM * kD;                      // M*D fp32
    float* slc_p = cmp_v + kM * kD;                      // T*NB fp32
    unsigned* sel_mask = (unsigned*)(slc_p + kT * kNB);  // T u32
    short* kb = (short*)(sel_mask + kT);                 // kKBRows*kD bf16
    short* vt = kb + (size_t)kKBRows * kD;               // kD*kVTCols bf16

    k_compress<<<dim3(kM), dim3(kD), 0, stream>>>(k, v, cmp_k, cmp_v);
    k_convert<<<dim3(kKBRows), dim3(kD), 0, stream>>>(k, v, kb, vt);
    k_cmp_attn<<<dim3(kT), dim3(256), 0, stream>>>(q, cw, cmp_k, cmp_v, slc_p, out);
    k_topk<<<dim3(kT / 256), dim3(256), 0, stream>>>(slc_p, sel_mask);
    k_attn_mfma<<<dim3(kT), dim3(256), 0, stream>>>(q, kb, vt, cw, sel_mask, out);
}

// Round 4
// 363.808 us; speedup vs baseline: 11.0706x; 1.0832x over previous
//
#include <hip/hip_runtime.h>
#include <math.h>

// ---- NSA hyperparameters (compile-time, matches reference config) ----
constexpr int kT    = 2048;
constexpr int kHQ   = 16;
constexpr int kD    = 128;
constexpr int kKS   = 32;
constexpr int kST   = 16;
constexpr int kBS   = 64;
constexpr int kM    = (kT - kKS) / kST + 1;   // 127 compressed tokens
constexpr int kNB   = (kT + kBS - 1) / kBS;   // 32 selection blocks
constexpr int kTopN = 16;
constexpr int kNInit = 2;
constexpr int kWIN  = 512;
constexpr float kNEG = -1e30f;
constexpr float kBIG = 1e30f;
constexpr float kScale = 0.08838834764831845f; // 128^-0.5

constexpr int kPad    = 32;
constexpr int kKBRows = kT + kPad; // 2080
constexpr int kVTCols = kT + kPad; // 2080

// K2 (scalar fp32 cmp-attn) LDS strides
constexpr int kQStride = kD + 4;   // 132
constexpr int kPStride = kM + 2;   // 129

// K4 strides: S fp32 [16][524], P bf16 [16][528] (16B-aligned rows)
constexpr int kSS4 = 524;
constexpr int kPS4 = 528;

typedef __attribute__((ext_vector_type(8))) short short8;
typedef __attribute__((ext_vector_type(4))) float floatx4;

// RNE float -> bf16 bits
__device__ inline short f2bf(float x) {
    unsigned u = __float_as_uint(x);
    unsigned r = (u + 0x7fffu + ((u >> 16) & 1u)) >> 16;
    return (short)r;
}

// ---------------------------------------------------------------------
// K1: mean-pool compressed K/V (fp32 — feeds the top-k-sensitive path).
// grid=(M), block=(D)
// ---------------------------------------------------------------------
__global__ void k_compress(const float* __restrict__ k, const float* __restrict__ v,
                           float* __restrict__ cmp_k, float* __restrict__ cmp_v) {
    const int m = blockIdx.x;
    const int d = threadIdx.x;
    float sk = 0.f, sv = 0.f;
    const int base = m * kST;
    #pragma unroll
    for (int i = 0; i < kKS; ++i) {
        sk += k[(size_t)(base + i) * kD + d];
        sv += v[(size_t)(base + i) * kD + d];
    }
    cmp_k[m * kD + d] = sk * (1.0f / kKS);
    cmp_v[m * kD + d] = sv * (1.0f / kKS);
}

// ---------------------------------------------------------------------
// K1b: fp32 -> bf16 staging for main attention.  kb[row][d] row-major,
// vt[d][row] transposed; rows/cols >= kT zeroed.  grid=(2080), block=(128)
// ---------------------------------------------------------------------
__global__ void k_convert(const float* __restrict__ k, const float* __restrict__ v,
                          short* __restrict__ kb, short* __restrict__ vt) {
    const int row = blockIdx.x;
    const int d = threadIdx.x;
    if (row < kT) {
        kb[row * kD + d] = f2bf(k[(size_t)row * kD + d]);
        vt[(size_t)d * kVTCols + row] = f2bf(v[(size_t)row * kD + d]);
    } else {
        kb[row * kD + d] = 0;
        vt[(size_t)d * kVTCols + row] = 0;
    }
}

// ---------------------------------------------------------------------
// K2: compressed attention, all 16 heads of one t — PURE FP32.
// The slc_p -> top-k path is selection-sensitive: bf16-level score error
// flips block choices vs the fp32 reference (R3 post-mortem). Keep fp32.
// grid=(T), block=(256)
// ---------------------------------------------------------------------
__global__ __launch_bounds__(256) void k_cmp_attn(
        const float* __restrict__ q, const float* __restrict__ cw,
        const float* __restrict__ cmp_k, const float* __restrict__ cmp_v,
        float* __restrict__ slc_p, float* __restrict__ out) {
    const int t = blockIdx.x;
    const int tid = threadIdx.x;

    __shared__ float q_s[kHQ * kQStride];
    __shared__ float p_s[kHQ * kPStride];

    for (int i = tid; i < kHQ * kD; i += 256) {
        int h = i >> 7, d = i & 127;
        q_s[h * kQStride + d] = q[(size_t)t * kHQ * kD + i];
    }
    __syncthreads();

    const int nvalid = (t >= kKS - 1) ? min(kM, (t - (kKS - 1)) / kST + 1) : 0;

    for (int idx = tid; idx < kHQ * kM; idx += 256) {
        const int m = idx / kHQ;
        const int h = idx % kHQ;
        float s = kNEG;
        if (m < nvalid) {
            const float4* k4 = (const float4*)(cmp_k + (size_t)m * kD);
            const float4* q4 = (const float4*)(q_s + h * kQStride);
            float acc = 0.f;
            #pragma unroll
            for (int i = 0; i < kD / 4; ++i) {
                float4 a = q4[i]; float4 b = k4[i];
                acc = fmaf(a.x, b.x, fmaf(a.y, b.y, fmaf(a.z, b.z, fmaf(a.w, b.w, acc))));
            }
            s = acc * kScale;
        }
        p_s[h * kPStride + m] = s;
    }
    __syncthreads();

    if (tid < kHQ) {
        float* p = p_s + tid * kPStride;
        if (nvalid == 0) {
            for (int m = 0; m < kM; ++m) p[m] = 0.f;
        } else {
            float mx = kNEG;
            for (int m = 0; m < nvalid; ++m) mx = fmaxf(mx, p[m]);
            float l = 0.f;
            for (int m = 0; m < nvalid; ++m) { float e = __expf(p[m] - mx); p[m] = e; l += e; }
            float inv = 1.f / l;
            for (int m = 0; m < nvalid; ++m) p[m] *= inv;
            for (int m = nvalid; m < kM; ++m) p[m] = 0.f;
        }
    }
    __syncthreads();

    for (int idx = tid; idx < kHQ * kD; idx += 256) {
        const int h = idx >> 7;
        const int d = idx & 127;
        const float* p = p_s + h * kPStride;
        float acc = 0.f;
        for (int m = 0; m < nvalid; ++m)
            acc = fmaf(p[m], cmp_v[(size_t)m * kD + d], acc);
        const float c0 = cw[((size_t)t * kHQ + h) * 3 + 0];
        const float w0 = 1.f / (1.f + __expf(-c0));
        out[((size_t)t * kHQ + h) * kD + d] = w0 * acc;
    }

    if (tid < kNB) {
        const int b = tid;
        const int m0 = 4 * b;
        float acc = 0.f;
        for (int h = 0; h < kHQ; ++h) {
            const float* p = p_s + h * kPStride;
            float a = 0.f;
            if (m0     < kM) a += p[m0];
            if (m0 + 1 < kM) a += p[m0 + 1];
            if (m0 + 2 < kM) a += p[m0 + 2];
            if (m0 + 3 < kM) a += 0.5f * p[m0 + 3];
            if (m0 - 1 >= 0) a += 0.5f * p[m0 - 1];
            acc += a;
        }
        slc_p[t * kNB + b] = acc;
    }
}

// ---------------------------------------------------------------------
// K3: top-k -> 32-bit block membership mask per t (always 16 bits set).
// ---------------------------------------------------------------------
__global__ void k_topk(const float* __restrict__ slc_p, unsigned* __restrict__ sel_mask) {
    const int t = blockIdx.x * blockDim.x + threadIdx.x;
    if (t >= kT) return;
    const int cur = t / kBS;
    float vals[kNB];
    #pragma unroll
    for (int b = 0; b < kNB; ++b) {
        float x = slc_p[t * kNB + b];
        if (b > cur) x = kNEG;
        if (b < kNInit || b == cur) x = kBIG;
        vals[b] = x;
    }
    unsigned mask = 0;
    for (int n = 0; n < kTopN; ++n) {
        float best = -3.0e38f; int bi = 0;
        #pragma unroll
        for (int b = 0; b < kNB; ++b) {
            bool taken = (mask >> b) & 1u;
            if (!taken && vals[b] > best) { best = vals[b]; bi = b; }
        }
        mask |= (1u << bi);
    }
    sel_mask[t] = mask;
}

// ---------------------------------------------------------------------
// Flash chunk: QK -> S[head][slot] -> online softmax (P bf16) -> PV.
// ntiles 16-key tiles (even).  o rescaled by alpha each chunk.
// ---------------------------------------------------------------------
__device__ __forceinline__ void attn_chunk(
        int t, int tid, const short8* aq,
        const short* __restrict__ kb, const short* __restrict__ vt,
        const int* blist, int base, bool is_sel, int ntiles,
        float* S, short* P, float* mrun, float* lrun, float* alpha_s,
        floatx4* o) {
    const int wave = tid >> 6;
    const int lane = tid & 63;
    const int l15 = lane & 15;
    const int quad = lane >> 4;

    // ---- QK ----
    for (int tau = wave; tau < ntiles; tau += 4) {
        const int key0 = is_sel ? blist[base + (tau >> 2)] * kBS + (tau & 3) * 16
                                : base + tau * 16;
        floatx4 acc = {0.f, 0.f, 0.f, 0.f};
        const short* kp = kb + (size_t)(key0 + l15) * kD + quad * 8;
        #pragma unroll
        for (int c = 0; c < 4; ++c)
            acc = __builtin_amdgcn_mfma_f32_16x16x32_bf16(aq[c], *(const short8*)(kp + c * 32), acc, 0, 0, 0);
        const bool ok = (key0 + l15) <= t;
        #pragma unroll
        for (int r = 0; r < 4; ++r)
            S[(quad * 4 + r) * kSS4 + tau * 16 + l15] = ok ? acc[r] * kScale : kNEG;
    }
    __syncthreads();

    // ---- online softmax: h = tid>>4, lanes j = l15 ----
    {
        const int h = tid >> 4;
        const int j = l15;
        const int ns = ntiles * 16;
        float mx = kNEG;
        for (int s = j * 4; s < ns; s += 64) {
            const float4 x = *(const float4*)&S[h * kSS4 + s];
            mx = fmaxf(mx, fmaxf(fmaxf(x.x, x.y), fmaxf(x.z, x.w)));
        }
        #pragma unroll
        for (int off = 8; off; off >>= 1) mx = fmaxf(mx, __shfl_xor(mx, off, 16));
        const float mprev = mrun[h];
        const float mnew = fmaxf(mprev, mx);
        const float alpha = __expf(mprev - mnew);
        float lsum = 0.f;
        for (int s = j * 4; s < ns; s += 64) {
            const float4 x = *(const float4*)&S[h * kSS4 + s];
            const float p0 = __expf(x.x - mnew), p1 = __expf(x.y - mnew);
            const float p2 = __expf(x.z - mnew), p3 = __expf(x.w - mnew);
            lsum += (p0 + p1) + (p2 + p3);
            short4 pb; pb.x = f2bf(p0); pb.y = f2bf(p1); pb.z = f2bf(p2); pb.w = f2bf(p3);
            *(short4*)&P[h * kPS4 + s] = pb;
        }
        #pragma unroll
        for (int off = 8; off; off >>= 1) lsum += __shfl_xor(lsum, off, 16);
        if (j == 0) { lrun[h] = lrun[h] * alpha + lsum; mrun[h] = mnew; alpha_s[h] = alpha; }
    }
    __syncthreads();

    // ---- PV (wave owns dims [32w, 32w+32)) ----
    const int dimbase = wave * 32;
    float ar[4];
    #pragma unroll
    for (int r = 0; r < 4; ++r) ar[r] = alpha_s[quad * 4 + r];
    #pragma unroll
    for (int nt = 0; nt < 2; ++nt)
        #pragma unroll
        for (int r = 0; r < 4; ++r) o[nt][r] *= ar[r];
    const int nkc = ntiles >> 1;
    for (int kc = 0; kc < nkc; ++kc) {
        const short8 ap = *(const short8*)&P[l15 * kPS4 + kc * 32 + quad * 8];
        const int keybase = is_sel ? blist[base + (kc >> 1)] * kBS + (kc & 1) * 32
                                   : base + kc * 32;
        #pragma unroll
        for (int nt = 0; nt < 2; ++nt) {
            const short8 b = *(const short8*)(vt + (size_t)(dimbase + nt * 16 + l15) * kVTCols + keybase + quad * 8);
            o[nt] = __builtin_amdgcn_mfma_f32_16x16x32_bf16(ap, b, o[nt], 0, 0, 0);
        }
    }
    // no trailing sync: next chunk's QK only writes S; its barrier protects P/state
}

// ---------------------------------------------------------------------
// K4: flash select + SWA attention, all 16 heads of one t.
// grid=(T), block=(256).  out += w1*sel_o + w2*swa_o
// ---------------------------------------------------------------------
__global__ __launch_bounds__(256, 3) void k_attn_flash(
        const float* __restrict__ q, const short* __restrict__ kb,
        const short* __restrict__ vt, const float* __restrict__ cw,
        const unsigned* __restrict__ sel_mask, float* __restrict__ out) {
    const int t = blockIdx.x;
    const int tid = threadIdx.x;
    const int wave = tid >> 6;
    const int lane = tid & 63;
    const int l15 = lane & 15;
    const int quad = lane >> 4;

    __shared__ float S[kHQ * kSS4];          // 33.5 KB
    __shared__ short P[kHQ * kPS4];          // 16.9 KB
    __shared__ int blist[kTopN];
    __shared__ float mrun[kHQ], lrun[kHQ], alpha_s[kHQ], inv_sel_s[kHQ];

    // A-fragments: q[t][head][.] bf16; head = l15, k = c*32 + quad*8 + j
    short8 aq[4];
    {
        const float* qp = q + ((size_t)t * kHQ + l15) * kD + quad * 8;
        #pragma unroll
        for (int c = 0; c < 4; ++c) {
            const float4 f0 = *(const float4*)(qp + c * 32);
            const float4 f1 = *(const float4*)(qp + c * 32 + 4);
            short8 a;
            a[0] = f2bf(f0.x); a[1] = f2bf(f0.y); a[2] = f2bf(f0.z); a[3] = f2bf(f0.w);
            a[4] = f2bf(f1.x); a[5] = f2bf(f1.y); a[6] = f2bf(f1.z); a[7] = f2bf(f1.w);
            aq[c] = a;
        }
    }

    if (tid == 0) {
        unsigned mask = sel_mask[t];
        int nb = 0;
        for (int b = 0; b < kNB; ++b)
            if ((mask >> b) & 1u) blist[nb++] = b;   // always 16
    }
    if (tid < kHQ) { mrun[tid] = kNEG; lrun[tid] = 0.f; }
    __syncthreads();

    // ---- SELECT: 2 chunks of 8 blocks (512 keys each) ----
    floatx4 osel[2] = {{0,0,0,0},{0,0,0,0}};
    attn_chunk(t, tid, aq, kb, vt, blist, 0, true, 32, S, P, mrun, lrun, alpha_s, osel);
    attn_chunk(t, tid, aq, kb, vt, blist, 8, true, 32, S, P, mrun, lrun, alpha_s, osel);

    if (tid < kHQ) {
        inv_sel_s[tid] = 1.f / lrun[tid];
        mrun[tid] = kNEG; lrun[tid] = 0.f;
    }

    // ---- SWA: one chunk of <=512 contiguous keys ----
    floatx4 oswa[2] = {{0,0,0,0},{0,0,0,0}};
    const int s0 = max(0, t - kWIN + 1);
    const int n = t - s0 + 1;
    const int ntiles_swa = (((n + 31) >> 5) << 1);   // even, NEG-masked tail
    attn_chunk(t, tid, aq, kb, vt, blist, s0, false, ntiles_swa, S, P, mrun, lrun, alpha_s, oswa);

    // ---- combine ----
    const int dimbase = wave * 32;
    #pragma unroll
    for (int r = 0; r < 4; ++r) {
        const int head = quad * 4 + r;
        const float c1 = cw[((size_t)t * kHQ + head) * 3 + 1];
        const float c2 = cw[((size_t)t * kHQ + head) * 3 + 2];
        const float w1 = 1.f / (1.f + __expf(-c1));
        const float w2 = 1.f / (1.f + __expf(-c2));
        const float is = inv_sel_s[head];
        const float iw = 1.f / lrun[head];
        #pragma unroll
        for (int nt = 0; nt < 2; ++nt) {
            const int dim = dimbase + nt * 16 + l15;
            float* op = out + ((size_t)t * kHQ + head) * kD + dim;
            *op += w1 * osel[nt][r] * is + w2 * oswa[nt][r] * iw;
        }
    }
}

// ---------------------------------------------------------------------
extern "C" void kernel_launch(void* const* d_in, const int* in_sizes, int n_in,
                              void* d_out, int out_size, void* d_ws, size_t ws_size,
                              hipStream_t stream) {
    const float* q  = (const float*)d_in[0];
    const float* k  = (const float*)d_in[1];
    const float* v  = (const float*)d_in[2];
    const float* cw = (const float*)d_in[3];
    float* out = (float*)d_out;

    float* ws = (float*)d_ws;
    float* cmp_k = ws;                                   // M*D fp32
    float* cmp_v = cmp_k + kM * kD;                      // M*D fp32
    float* slc_p = cmp_v + kM * kD;                      // T*NB fp32
    unsigned* sel_mask = (unsigned*)(slc_p + kT * kNB);  // T u32
    short* kb = (short*)(sel_mask + kT);                 // kKBRows*kD bf16
    short* vt = kb + (size_t)kKBRows * kD;               // kD*kVTCols bf16

    k_compress<<<dim3(kM), dim3(kD), 0, stream>>>(k, v, cmp_k, cmp_v);
    k_convert<<<dim3(kKBRows), dim3(kD), 0, stream>>>(k, v, kb, vt);
    k_cmp_attn<<<dim3(kT), dim3(256), 0, stream>>>(q, cw, cmp_k, cmp_v, slc_p, out);
    k_topk<<<dim3(kT / 256), dim3(256), 0, stream>>>(slc_p, sel_mask);
    k_attn_flash<<<dim3(kT), dim3(256), 0, stream>>>(q, kb, vt, cw, sel_mask, out);
}

// Round 5
// 313.315 us; speedup vs baseline: 12.8547x; 1.1612x over previous
//
#include <hip/hip_runtime.h>
#include <math.h>

// ---- NSA hyperparameters (compile-time, matches reference config) ----
constexpr int kT    = 2048;
constexpr int kHQ   = 16;
constexpr int kD    = 128;
constexpr int kKS   = 32;
constexpr int kST   = 16;
constexpr int kBS   = 64;
constexpr int kM    = (kT - kKS) / kST + 1;   // 127 compressed tokens
constexpr int kNB   = (kT + kBS - 1) / kBS;   // 32 selection blocks
constexpr int kTopN = 16;
constexpr int kNInit = 2;
constexpr int kWIN  = 512;
constexpr float kNEG = -1e30f;
constexpr float kBIG = 1e30f;
constexpr float kScale = 0.08838834764831845f; // 128^-0.5

constexpr int kPad    = 32;
constexpr int kKBRows = kT + kPad; // 2080
constexpr int kVTCols = kT + kPad; // 2080

// K2 (cmp-attn) LDS strides
constexpr int kQS2 = kD + 4;   // 132 floats (16B-aligned rows)
constexpr int kPS2 = 132;      // fp32 probs, cols 0..127 used
constexpr int kPB2 = 136;      // bf16 probs (272 B row, 16B-aligned)

// K4 (flash) strides: 256-key chunks.  S fp32 [16][260], P bf16 [16][264]
constexpr int kSS4 = 260;
constexpr int kPS4 = 264;

typedef __attribute__((ext_vector_type(8))) short short8;
typedef __attribute__((ext_vector_type(4))) float floatx4;

// RNE float -> bf16 bits
__device__ inline short f2bf(float x) {
    unsigned u = __float_as_uint(x);
    unsigned r = (u + 0x7fffu + ((u >> 16) & 1u)) >> 16;
    return (short)r;
}

// ---------------------------------------------------------------------
// K1: fused staging.  blocks [0,2080): bf16 K rows + V^T cols for flash.
// blocks [2080,2208): mean-pool cmp_k (fp32, feeds top-k-sensitive QK)
// and cmp V^T bf16 (feeds tolerance-checked MFMA PV).  block=(128)
// ---------------------------------------------------------------------
__global__ void k_stage(const float* __restrict__ k, const float* __restrict__ v,
                        short* __restrict__ kb, short* __restrict__ vt,
                        float* __restrict__ cmp_k, short* __restrict__ cvt) {
    const int bid = blockIdx.x;
    const int d = threadIdx.x;
    if (bid < kKBRows) {
        const int row = bid;
        if (row < kT) {
            kb[row * kD + d] = f2bf(k[(size_t)row * kD + d]);
            vt[(size_t)d * kVTCols + row] = f2bf(v[(size_t)row * kD + d]);
        } else {
            kb[row * kD + d] = 0;
            vt[(size_t)d * kVTCols + row] = 0;
        }
    } else {
        const int m = bid - kKBRows;        // 0..127 (127 = zero pad row)
        float sk = 0.f, sv = 0.f;
        if (m < kM) {
            const int base = m * kST;
            #pragma unroll
            for (int i = 0; i < kKS; ++i) {
                sk += k[(size_t)(base + i) * kD + d];
                sv += v[(size_t)(base + i) * kD + d];
            }
            sk *= (1.0f / kKS);
            sv *= (1.0f / kKS);
        }
        cmp_k[m * kD + d] = sk;
        cvt[d * 128 + m] = f2bf(sv);
    }
}

// ---------------------------------------------------------------------
// K2: compressed attention, all 16 heads of one t.
// QK + softmax + slc_p: fp32, arithmetic bitwise-identical to R4
// (selection-sensitive — R3 showed bf16-level score error flips top-k).
// PV: bf16 MFMA (downstream of selection, tolerance-checked path).
// grid=(T), block=(256)
// ---------------------------------------------------------------------
__global__ __launch_bounds__(256) void k_cmp_attn(
        const float* __restrict__ q, const float* __restrict__ cw,
        const float* __restrict__ cmp_k, const short* __restrict__ cvt,
        float* __restrict__ slc_p, float* __restrict__ out) {
    const int t = blockIdx.x;
    const int tid = threadIdx.x;
    const int wave = tid >> 6;
    const int lane = tid & 63;
    const int l15 = lane & 15;
    const int quad = lane >> 4;

    __shared__ float q_s[kHQ * kQS2];   // 8.4 KB
    __shared__ float p_s[kHQ * kPS2];   // 8.4 KB  scores -> normalized probs
    __shared__ short Pb[kHQ * kPB2];    // 4.4 KB  bf16 normalized probs

    for (int i = tid; i < kHQ * kD; i += 256) {
        int h = i >> 7, d = i & 127;
        q_s[h * kQS2 + d] = q[(size_t)t * kHQ * kD + i];
    }
    __syncthreads();

    const int nvalid = (t >= kKS - 1) ? min(kM, (t - (kKS - 1)) / kST + 1) : 0;

    // ---- QK: thread handles one m x 4 heads (4 independent fmaf chains,
    //      each chain's order identical to R4's single-dot chain) ----
    for (int idx = tid; idx < nvalid * 4; idx += 256) {
        const int m = idx >> 2;
        const int h0 = (idx & 3) * 4;
        const float4* k4 = (const float4*)(cmp_k + (size_t)m * kD);
        float a0 = 0.f, a1 = 0.f, a2 = 0.f, a3 = 0.f;
        #pragma unroll
        for (int i = 0; i < kD / 4; ++i) {
            const float4 b = k4[i];
            const float4 qa = *(const float4*)&q_s[(h0 + 0) * kQS2 + i * 4];
            const float4 qb = *(const float4*)&q_s[(h0 + 1) * kQS2 + i * 4];
            const float4 qc = *(const float4*)&q_s[(h0 + 2) * kQS2 + i * 4];
            const float4 qd = *(const float4*)&q_s[(h0 + 3) * kQS2 + i * 4];
            a0 = fmaf(qa.x, b.x, fmaf(qa.y, b.y, fmaf(qa.z, b.z, fmaf(qa.w, b.w, a0))));
            a1 = fmaf(qb.x, b.x, fmaf(qb.y, b.y, fmaf(qb.z, b.z, fmaf(qb.w, b.w, a1))));
            a2 = fmaf(qc.x, b.x, fmaf(qc.y, b.y, fmaf(qc.z, b.z, fmaf(qc.w, b.w, a2))));
            a3 = fmaf(qd.x, b.x, fmaf(qd.y, b.y, fmaf(qd.z, b.z, fmaf(qd.w, b.w, a3))));
        }
        p_s[(h0 + 0) * kPS2 + m] = a0 * kScale;
        p_s[(h0 + 1) * kPS2 + m] = a1 * kScale;
        p_s[(h0 + 2) * kPS2 + m] = a2 * kScale;
        p_s[(h0 + 3) * kPS2 + m] = a3 * kScale;
    }
    __syncthreads();

    // ---- softmax: serial per head, bitwise-identical to R4 ----
    if (tid < kHQ) {
        float* p = p_s + tid * kPS2;
        short* pb = Pb + tid * kPB2;
        if (nvalid == 0) {
            for (int m = 0; m < 128; ++m) { p[m] = 0.f; pb[m] = 0; }
        } else {
            float mx = kNEG;
            for (int m = 0; m < nvalid; ++m) mx = fmaxf(mx, p[m]);
            float l = 0.f;
            for (int m = 0; m < nvalid; ++m) { float e = __expf(p[m] - mx); p[m] = e; l += e; }
            float inv = 1.f / l;
            for (int m = 0; m < nvalid; ++m) { float pn = p[m] * inv; p[m] = pn; pb[m] = f2bf(pn); }
            for (int m = nvalid; m < 128; ++m) { p[m] = 0.f; pb[m] = 0; }
        }
    }
    __syncthreads();

    // ---- slc_p (identical expression to R4) ----
    if (tid < kNB) {
        const int b = tid;
        const int m0 = 4 * b;
        float acc = 0.f;
        for (int h = 0; h < kHQ; ++h) {
            const float* p = p_s + h * kPS2;
            float a = 0.f;
            a += p[m0];
            a += p[m0 + 1];
            a += p[m0 + 2];
            a += 0.5f * p[m0 + 3];        // index 127 is zero-filled
            if (m0 - 1 >= 0) a += 0.5f * p[m0 - 1];
            acc += a;
        }
        slc_p[t * kNB + b] = acc;
    }

    // ---- PV via MFMA: wave owns dims [32w, 32w+32) ----
    const int dimbase = wave * 32;
    floatx4 o[2] = {{0,0,0,0},{0,0,0,0}};
    #pragma unroll
    for (int kc = 0; kc < 4; ++kc) {
        const short8 ap = *(const short8*)&Pb[l15 * kPB2 + kc * 32 + quad * 8];
        #pragma unroll
        for (int nt = 0; nt < 2; ++nt) {
            const short8 b = *(const short8*)(cvt + (size_t)(dimbase + nt * 16 + l15) * 128 + kc * 32 + quad * 8);
            o[nt] = __builtin_amdgcn_mfma_f32_16x16x32_bf16(ap, b, o[nt], 0, 0, 0);
        }
    }

    #pragma unroll
    for (int r = 0; r < 4; ++r) {
        const int head = quad * 4 + r;
        const float c0 = cw[((size_t)t * kHQ + head) * 3 + 0];
        const float w0 = 1.f / (1.f + __expf(-c0));
        #pragma unroll
        for (int nt = 0; nt < 2; ++nt)
            out[((size_t)t * kHQ + head) * kD + dimbase + nt * 16 + l15] = w0 * o[nt][r];
    }
}

// ---------------------------------------------------------------------
// K3: top-k -> 32-bit block membership mask per t (always 16 bits set).
// ---------------------------------------------------------------------
__global__ void k_topk(const float* __restrict__ slc_p, unsigned* __restrict__ sel_mask) {
    const int t = blockIdx.x * blockDim.x + threadIdx.x;
    if (t >= kT) return;
    const int cur = t / kBS;
    float vals[kNB];
    #pragma unroll
    for (int b = 0; b < kNB; ++b) {
        float x = slc_p[t * kNB + b];
        if (b > cur) x = kNEG;
        if (b < kNInit || b == cur) x = kBIG;
        vals[b] = x;
    }
    unsigned mask = 0;
    for (int n = 0; n < kTopN; ++n) {
        float best = -3.0e38f; int bi = 0;
        #pragma unroll
        for (int b = 0; b < kNB; ++b) {
            bool taken = (mask >> b) & 1u;
            if (!taken && vals[b] > best) { best = vals[b]; bi = b; }
        }
        mask |= (1u << bi);
    }
    sel_mask[t] = mask;
}

// ---------------------------------------------------------------------
// Flash chunk (256 keys): QK -> S[head][slot] -> online softmax (P bf16)
// -> PV.  ntiles (even, <=16) 16-key tiles.  o rescaled by alpha.
// is_sel: base = offset into blist (chunk of 4 blocks); else key base.
// ---------------------------------------------------------------------
__device__ __forceinline__ void attn_chunk(
        int t, int tid, const short8* aq,
        const short* __restrict__ kb, const short* __restrict__ vt,
        const int* blist, int base, bool is_sel, int ntiles,
        float* S, short* P, float* mrun, float* lrun, float* alpha_s,
        floatx4* o) {
    const int wave = tid >> 6;
    const int lane = tid & 63;
    const int l15 = lane & 15;
    const int quad = lane >> 4;

    // ---- QK ----
    for (int tau = wave; tau < ntiles; tau += 4) {
        const int key0 = is_sel ? blist[base + (tau >> 2)] * kBS + (tau & 3) * 16
                                : base + tau * 16;
        floatx4 acc = {0.f, 0.f, 0.f, 0.f};
        const short* kp = kb + (size_t)(key0 + l15) * kD + quad * 8;
        #pragma unroll
        for (int c = 0; c < 4; ++c)
            acc = __builtin_amdgcn_mfma_f32_16x16x32_bf16(aq[c], *(const short8*)(kp + c * 32), acc, 0, 0, 0);
        const bool ok = (key0 + l15) <= t;
        #pragma unroll
        for (int r = 0; r < 4; ++r)
            S[(quad * 4 + r) * kSS4 + tau * 16 + l15] = ok ? acc[r] * kScale : kNEG;
    }
    __syncthreads();

    // ---- online softmax: h = tid>>4, lanes j = l15 ----
    {
        const int h = tid >> 4;
        const int j = l15;
        const int ns = ntiles * 16;
        float mx = kNEG;
        for (int s = j * 4; s < ns; s += 64) {
            const float4 x = *(const float4*)&S[h * kSS4 + s];
            mx = fmaxf(mx, fmaxf(fmaxf(x.x, x.y), fmaxf(x.z, x.w)));
        }
        #pragma unroll
        for (int off = 8; off; off >>= 1) mx = fmaxf(mx, __shfl_xor(mx, off, 16));
        const float mprev = mrun[h];
        const float mnew = fmaxf(mprev, mx);
        const float alpha = __expf(mprev - mnew);
        float lsum = 0.f;
        for (int s = j * 4; s < ns; s += 64) {
            const float4 x = *(const float4*)&S[h * kSS4 + s];
            const float p0 = __expf(x.x - mnew), p1 = __expf(x.y - mnew);
            const float p2 = __expf(x.z - mnew), p3 = __expf(x.w - mnew);
            lsum += (p0 + p1) + (p2 + p3);
            short4 pb; pb.x = f2bf(p0); pb.y = f2bf(p1); pb.z = f2bf(p2); pb.w = f2bf(p3);
            *(short4*)&P[h * kPS4 + s] = pb;
        }
        #pragma unroll
        for (int off = 8; off; off >>= 1) lsum += __shfl_xor(lsum, off, 16);
        if (j == 0) { lrun[h] = lrun[h] * alpha + lsum; mrun[h] = mnew; alpha_s[h] = alpha; }
    }
    __syncthreads();

    // ---- PV (wave owns dims [32w, 32w+32)) ----
    const int dimbase = wave * 32;
    float ar[4];
    #pragma unroll
    for (int r = 0; r < 4; ++r) ar[r] = alpha_s[quad * 4 + r];
    #pragma unroll
    for (int nt = 0; nt < 2; ++nt)
        #pragma unroll
        for (int r = 0; r < 4; ++r) o[nt][r] *= ar[r];
    const int nkc = ntiles >> 1;
    for (int kc = 0; kc < nkc; ++kc) {
        const short8 ap = *(const short8*)&P[l15 * kPS4 + kc * 32 + quad * 8];
        const int keybase = is_sel ? blist[base + (kc >> 1)] * kBS + (kc & 1) * 32
                                   : base + kc * 32;
        #pragma unroll
        for (int nt = 0; nt < 2; ++nt) {
            const short8 b = *(const short8*)(vt + (size_t)(dimbase + nt * 16 + l15) * kVTCols + keybase + quad * 8);
            o[nt] = __builtin_amdgcn_mfma_f32_16x16x32_bf16(ap, b, o[nt], 0, 0, 0);
        }
    }
    // no trailing sync: next chunk's QK only writes S; its barrier orders P/state
}

// ---------------------------------------------------------------------
// K4: flash select + SWA attention, all 16 heads of one t.
// grid=(T), block=(256), ~25 KB LDS -> 6 blocks/CU.
// ---------------------------------------------------------------------
__global__ __launch_bounds__(256, 6) void k_attn_flash(
        const float* __restrict__ q, const short* __restrict__ kb,
        const short* __restrict__ vt, const float* __restrict__ cw,
        const unsigned* __restrict__ sel_mask, float* __restrict__ out) {
    const int t = blockIdx.x;
    const int tid = threadIdx.x;
    const int wave = tid >> 6;
    const int lane = tid & 63;
    const int l15 = lane & 15;
    const int quad = lane >> 4;

    __shared__ float S[kHQ * kSS4];          // 16.6 KB
    __shared__ short P[kHQ * kPS4];          // 8.4 KB
    __shared__ int blist[kTopN];
    __shared__ float mrun[kHQ], lrun[kHQ], alpha_s[kHQ], inv_sel_s[kHQ];

    // A-fragments: q[t][head][.] bf16; head = l15, k = c*32 + quad*8 + j
    short8 aq[4];
    {
        const float* qp = q + ((size_t)t * kHQ + l15) * kD + quad * 8;
        #pragma unroll
        for (int c = 0; c < 4; ++c) {
            const float4 f0 = *(const float4*)(qp + c * 32);
            const float4 f1 = *(const float4*)(qp + c * 32 + 4);
            short8 a;
            a[0] = f2bf(f0.x); a[1] = f2bf(f0.y); a[2] = f2bf(f0.z); a[3] = f2bf(f0.w);
            a[4] = f2bf(f1.x); a[5] = f2bf(f1.y); a[6] = f2bf(f1.z); a[7] = f2bf(f1.w);
            aq[c] = a;
        }
    }

    if (tid == 0) {
        unsigned mask = sel_mask[t];
        int nb = 0;
        for (int b = 0; b < kNB; ++b)
            if ((mask >> b) & 1u) blist[nb++] = b;   // always 16
    }
    if (tid < kHQ) { mrun[tid] = kNEG; lrun[tid] = 0.f; }
    __syncthreads();

    // ---- SELECT: 4 chunks of 4 blocks (256 keys each) ----
    floatx4 osel[2] = {{0,0,0,0},{0,0,0,0}};
    #pragma unroll
    for (int c = 0; c < 4; ++c)
        attn_chunk(t, tid, aq, kb, vt, blist, c * 4, true, 16, S, P, mrun, lrun, alpha_s, osel);

    if (tid < kHQ) {
        inv_sel_s[tid] = 1.f / lrun[tid];
        mrun[tid] = kNEG; lrun[tid] = 0.f;
    }

    // ---- SWA: chunks of <=256 contiguous keys ----
    floatx4 oswa[2] = {{0,0,0,0},{0,0,0,0}};
    const int s0 = max(0, t - kWIN + 1);
    const int n = t - s0 + 1;
    const int TT = (((n + 31) >> 5) << 1);   // total 16-key tiles (even)
    for (int c0 = 0; c0 < TT; c0 += 16) {
        const int nt = min(16, TT - c0);
        attn_chunk(t, tid, aq, kb, vt, blist, s0 + c0 * 16, false, nt, S, P, mrun, lrun, alpha_s, oswa);
    }

    // ---- combine ----
    const int dimbase = wave * 32;
    #pragma unroll
    for (int r = 0; r < 4; ++r) {
        const int head = quad * 4 + r;
        const float c1 = cw[((size_t)t * kHQ + head) * 3 + 1];
        const float c2 = cw[((size_t)t * kHQ + head) * 3 + 2];
        const float w1 = 1.f / (1.f + __expf(-c1));
        const float w2 = 1.f / (1.f + __expf(-c2));
        const float is = inv_sel_s[head];
        const float iw = 1.f / lrun[head];
        #pragma unroll
        for (int nt = 0; nt < 2; ++nt) {
            const int dim = dimbase + nt * 16 + l15;
            float* op = out + ((size_t)t * kHQ + head) * kD + dim;
            *op += w1 * osel[nt][r] * is + w2 * oswa[nt][r] * iw;
        }
    }
}

// ---------------------------------------------------------------------
extern "C" void kernel_launch(void* const* d_in, const int* in_sizes, int n_in,
                              void* d_out, int out_size, void* d_ws, size_t ws_size,
                              hipStream_t stream) {
    const float* q  = (const float*)d_in[0];
    const float* k  = (const float*)d_in[1];
    const float* v  = (const float*)d_in[2];
    const float* cw = (const float*)d_in[3];
    float* out = (float*)d_out;

    float* ws = (float*)d_ws;
    float* cmp_k = ws;                                   // 128*128 fp32
    float* slc_p = cmp_k + 128 * kD;                     // T*NB fp32
    unsigned* sel_mask = (unsigned*)(slc_p + kT * kNB);  // T u32
    short* kb  = (short*)(sel_mask + kT);                // kKBRows*kD bf16
    short* vt  = kb + (size_t)kKBRows * kD;              // kD*kVTCols bf16
    short* cvt = vt + (size_t)kD * kVTCols;              // 128*128 bf16

    k_stage<<<dim3(kKBRows + 128), dim3(kD), 0, stream>>>(k, v, kb, vt, cmp_k, cvt);
    k_cmp_attn<<<dim3(kT), dim3(256), 0, stream>>>(q, cw, cmp_k, cvt, slc_p, out);
    k_topk<<<dim3(kT / 256), dim3(256), 0, stream>>>(slc_p, sel_mask);
    k_attn_flash<<<dim3(kT), dim3(256), 0, stream>>>(q, kb, vt, cw, sel_mask, out);
}